// Round 8
// baseline (64.035 us; speedup 1.0000x reference)
//
#include <hip/hip_runtime.h>

// IntSoftmax_Piecewise: integer softmax with piecewise deg-2 int-exp.
// out[r*1024+j] = softmax_int/128 ; out[rows*1024] = s_out = 1/128.
// The straight-through float-softmax combine in the reference is the identity
// on si, so the float softmax is never computed.
//
// Round-8 structure (threshold path):
//  - The e-table (e = floor(max(Horner,0)/2^15)) is a 2-level step function
//    ({0,1,2}) because Horner = 2^16*ys(x), ys in [0,1]. The build kernel
//    finds t1,t2 and VERIFIES table[i] == (i>=t1)+(i>=t2) for all i; on
//    success the main kernel uses two compares per element instead of an LDS
//    gather. On failure (flag) every block falls back to the exact gather
//    path, so correctness never depends on this structure.
//  - e_k via compare on q_k = RN(x/s) directly: floor(q)>=T <=> q>=T (T int).
//  - row sum via ballot+popcount (SALU) — no float sum shuffle tree.
//  - output = cndmask-select of {0, w1, w2}, w_e = floor(RN(e*factor)*2^-25)
//    * 2^-7 computed once per row (all pow2 scalings exact).
//  - Markstein correctly-rounded division: q0=RN(x*r); q=RN(fma(fma(-s,q0,x),
//    r,q0)) == RN(x/s), r=RN(1/s).
//  - rows with any element below table range take the exact direct path
//    (wave-uniform; never taken for this data).

constexpr int ROW = 1024;
constexpr int WPB = 4;        // one row per wave, 4 waves per 256-thread block
constexpr int TSIZE = 2048;   // table covers xv in [-(TSIZE-1), 0]

typedef float f32x4 __attribute__((ext_vector_type(4)));

// exact reference per-element int-exp (segment scan + Horner + clip + >>15)
__device__ __forceinline__ float eval_e(float xv,
                                        const float* __restrict__ lo,
                                        const float4* __restrict__ cf) {
    int seg = 0;
#pragma unroll
    for (int j = 1; j < 16; ++j) seg += (xv >= lo[j]) ? 1 : 0;
    const float4 c = cf[seg];
    float r = __fadd_rn(__fmul_rn(c.x, xv), c.y);
    r = __fadd_rn(__fmul_rn(r, xv), c.z);
    return floorf(fmaxf(r, 0.0f) * (1.0f / 32768.0f));
}

// one block, 256 threads: build table into gtab[0..2047], then find and
// verify the step thresholds; gtab[2048]=t1-2047, gtab[2049]=t2-2047,
// gtab[2050]=ok flag.
__global__ __launch_bounds__(256) void build_etab_kernel(
    const float* __restrict__ lo_bounds,
    const float* __restrict__ coeffs,
    float* __restrict__ gtab)
{
    __shared__ float stab[TSIZE];
    __shared__ int s_t1, s_t2, s_ok;
    const int tid = threadIdx.x;
    if (tid == 0) { s_t1 = TSIZE; s_t2 = TSIZE; s_ok = 1; }

    float lo[16];
    float4 cf[16];
#pragma unroll
    for (int j = 0; j < 16; ++j) {
        lo[j] = lo_bounds[j];
        cf[j] = make_float4(coeffs[j*3+0], coeffs[j*3+1], coeffs[j*3+2], 0.0f);
    }
    __syncthreads();

    for (int i = tid; i < TSIZE; i += 256) {
        const float e = eval_e((float)(i - (TSIZE - 1)), lo, cf);
        stab[i] = e;
        gtab[i] = e;
        if (e >= 1.0f) atomicMin(&s_t1, i);
        if (e >= 2.0f) atomicMin(&s_t2, i);
    }
    __syncthreads();
    for (int i = tid; i < TSIZE; i += 256) {
        const float want = (float)((i >= s_t1 ? 1 : 0) + (i >= s_t2 ? 1 : 0));
        if (stab[i] != want) s_ok = 0;   // benign race: all writers store 0
    }
    __syncthreads();
    if (tid == 0) {
        gtab[TSIZE + 0] = (float)(s_t1 - (TSIZE - 1));  // threshold offsets
        gtab[TSIZE + 1] = (float)(s_t2 - (TSIZE - 1));  // (integer-valued)
        gtab[TSIZE + 2] = (float)s_ok;
    }
}

__global__ __launch_bounds__(256) void intsoftmax_kernel(
    const float* __restrict__ x,
    const float* __restrict__ s_ptr,
    const float* __restrict__ lo_bounds,
    const float* __restrict__ coeffs,
    const float* __restrict__ gtab,
    float* __restrict__ out,
    int rows)
{
    __shared__ float etab[TSIZE];
    const int tid = threadIdx.x;

    const float okf = gtab[TSIZE + 2];
    const bool fast = (okf != 0.0f);          // grid-uniform
    if (!fast) {
        // stage full table for the gather fallback
        const f32x4* __restrict__ gt = (const f32x4*)gtab;
        f32x4* lt = (f32x4*)etab;
        lt[tid]       = gt[tid];
        lt[tid + 256] = gt[tid + 256];
        __syncthreads();
    }

    if (blockIdx.x == 0 && tid == 0) {
        out[(size_t)rows * ROW] = 0.0078125f;  // second tuple output: s_out
    }

    const float s = s_ptr[0];
    const float rcp = __fdiv_rn(1.0f, s);      // RN(1/s), once
    const float t1off = gtab[TSIZE + 0];
    const float t2off = gtab[TSIZE + 1];

    const int wave = tid >> 6;
    const int lane = tid & 63;
    const long long row = (long long)blockIdx.x * WPB + wave;
    if (row >= rows) return;

    const float4* __restrict__ xr = (const float4*)(x + row * (long long)ROW);

    // q = RN(x/s) via Markstein correctly-rounded division (no floor needed:
    // floor(q) >= T  <=>  q >= T for integer T; max/min floored once below)
    float q[16];
#pragma unroll
    for (int c4 = 0; c4 < 4; ++c4) {
        const float4 v = xr[c4 * 64 + lane];
        {
            const float q0 = __fmul_rn(v.x, rcp);
            q[c4*4+0] = __builtin_fmaf(__builtin_fmaf(-s, q0, v.x), rcp, q0);
        }
        {
            const float q0 = __fmul_rn(v.y, rcp);
            q[c4*4+1] = __builtin_fmaf(__builtin_fmaf(-s, q0, v.y), rcp, q0);
        }
        {
            const float q0 = __fmul_rn(v.z, rcp);
            q[c4*4+2] = __builtin_fmaf(__builtin_fmaf(-s, q0, v.z), rcp, q0);
        }
        {
            const float q0 = __fmul_rn(v.w, rcp);
            q[c4*4+3] = __builtin_fmaf(__builtin_fmaf(-s, q0, v.w), rcp, q0);
        }
    }

    // interleaved max/min trees (min only gates the range check)
    float mx = q[0], mn = q[0];
#pragma unroll
    for (int k = 1; k < 16; ++k) { mx = fmaxf(mx, q[k]); mn = fminf(mn, q[k]); }
#pragma unroll
    for (int off = 32; off >= 1; off >>= 1) {
        const float tx = __shfl_xor(mx, off, 64);
        const float tn = __shfl_xor(mn, off, 64);
        mx = fmaxf(mx, tx);
        mn = fminf(mn, tn);
    }
    const float m = floorf(mx);        // row max of x_int (exact)
    // max(floor(q)) == floor(max q); min likewise (floor monotone)
    const bool inrange = ((int)floorf(mn) - (int)m) + (TSIZE - 1) >= 0;

    f32x4* const orow_v = (f32x4*)(out + row * (long long)ROW);

    if (__builtin_expect(fast && inrange, 1)) {
        // thresholds in q-space for this row (all integer-valued, exact adds)
        const float T1 = __fadd_rn(t1off, m);
        const float T2 = __fadd_rn(t2off, m);

        // row sum of e via ballot+popcount (exact integer, order-free)
        int cnt = 0;
#pragma unroll
        for (int k = 0; k < 16; ++k) {
            cnt += __popcll(__ballot(q[k] >= T1));
            cnt += __popcll(__ballot(q[k] >= T2));
        }
        const float sum = fmaxf((float)cnt, 1.0f);   // exact (cnt <= 2048)
        const float factor = floorf(__fdiv_rn(4294967296.0f, sum));
        const float f25 = factor * (1.0f / 33554432.0f);          // exact pow2
        const float w1 = floorf(f25) * 0.0078125f;                // e=1 output
        const float w2 = floorf(__fmul_rn(2.0f, f25)) * 0.0078125f; // e=2

#pragma unroll
        for (int c4 = 0; c4 < 4; ++c4) {
            f32x4 o;
            o.x = (q[c4*4+0] >= T1) ? ((q[c4*4+0] >= T2) ? w2 : w1) : 0.0f;
            o.y = (q[c4*4+1] >= T1) ? ((q[c4*4+1] >= T2) ? w2 : w1) : 0.0f;
            o.z = (q[c4*4+2] >= T1) ? ((q[c4*4+2] >= T2) ? w2 : w1) : 0.0f;
            o.w = (q[c4*4+3] >= T1) ? ((q[c4*4+3] >= T2) ? w2 : w1) : 0.0f;
            __builtin_nontemporal_store(o, orow_v + c4 * 64 + lane);
        }
    } else {
        // exact general path (wave-uniform; taken only if verification failed
        // or a row exceeds the table range)
        float e[16];
        float psum = 0.0f;
        if (!fast && inrange) {
            const int base = (TSIZE - 1) - (int)m;
#pragma unroll
            for (int k = 0; k < 16; ++k) {
                e[k] = etab[(int)floorf(q[k]) + base];
                psum += e[k];
            }
        } else {
            float lo[16];
            float4 cf[16];
#pragma unroll
            for (int j = 0; j < 16; ++j) {
                lo[j] = lo_bounds[j];
                cf[j] = make_float4(coeffs[j*3+0], coeffs[j*3+1], coeffs[j*3+2], 0.0f);
            }
#pragma unroll
            for (int k = 0; k < 16; ++k) {
                e[k] = eval_e(floorf(q[k]) - m, lo, cf);
                psum += e[k];
            }
        }
        float sum = psum;
#pragma unroll
        for (int off = 32; off >= 1; off >>= 1)
            sum += __shfl_xor(sum, off, 64);
        const float factor = floorf(__fdiv_rn(4294967296.0f, fmaxf(sum, 1.0f)));
        const float f25 = factor * (1.0f / 33554432.0f);
#pragma unroll
        for (int c4 = 0; c4 < 4; ++c4) {
            f32x4 o;
            o.x = floorf(__fmul_rn(e[c4*4+0], f25)) * 0.0078125f;
            o.y = floorf(__fmul_rn(e[c4*4+1], f25)) * 0.0078125f;
            o.z = floorf(__fmul_rn(e[c4*4+2], f25)) * 0.0078125f;
            o.w = floorf(__fmul_rn(e[c4*4+3], f25)) * 0.0078125f;
            __builtin_nontemporal_store(o, orow_v + c4 * 64 + lane);
        }
    }
}

extern "C" void kernel_launch(void* const* d_in, const int* in_sizes, int n_in,
                              void* d_out, int out_size, void* d_ws, size_t ws_size,
                              hipStream_t stream) {
    const float* x      = (const float*)d_in[0];
    const float* s      = (const float*)d_in[1];
    const float* lo     = (const float*)d_in[2];
    // d_in[3] = hi_bounds (unused: segments contiguous, lo alone decides)
    const float* coeffs = (const float*)d_in[4];
    float* out = (float*)d_out;

    const int n = in_sizes[0];
    const int rows = n / ROW;
    const int blocks = (rows + WPB - 1) / WPB;

    // needs (TSIZE+3) floats of workspace; ws is guaranteed larger, but keep
    // a defensive check consistent with earlier rounds
    float* gtab = (float*)d_ws;
    hipLaunchKernelGGL(build_etab_kernel, dim3(1), dim3(256), 0, stream,
                       lo, coeffs, gtab);
    hipLaunchKernelGGL(intsoftmax_kernel, dim3(blocks), dim3(256), 0, stream,
                       x, s, lo, coeffs, gtab, out, rows);
}

// Round 9
// 59.428 us; speedup vs baseline: 1.0775x; 1.0775x over previous
//
#include <hip/hip_runtime.h>

// IntSoftmax_Piecewise: integer softmax with piecewise deg-2 int-exp.
// out[r*1024+j] = softmax_int/128 ; out[rows*1024] = s_out = 1/128.
// The reference's straight-through float-softmax combine is the identity on
// si, so the float softmax is never computed.
//
// ROOFLINE KERNEL (round-4 config, best measured 59.5 us):
//  - 398 MB mandatory f32 traffic (201 read + 197 write) at ~6.8 TB/s mixed
//    stream = memory floor. Rounds 5-8 proved VALU cut / prefetch / 2-row
//    ILP / LDS-free threshold path are all duration-neutral-or-worse.
//  - e(xv) = floor(max(Horner(xv),0)/2^15) precomputed into a 2048-entry LDS
//    table per block (exact reference f32 ops => bit-identical), 1 ds_read
//    per element.
//  - floor(x/s) via Markstein correctly-rounded FMA division:
//    r=RN(1/s); q0=RN(x*r); q=RN(fma(fma(-s,q0,x), r, q0)) == RN(x/s).
//  - xv below table range -> exact wave-uniform fallback (never taken for
//    sane data; correctness independent of data range).

constexpr int ROW = 1024;
constexpr int WPB = 4;        // one row per wave, 4 waves per 256-thread block
constexpr int TSIZE = 2048;   // table covers xv in [-(TSIZE-1), 0]

typedef float f32x4 __attribute__((ext_vector_type(4)));

__global__ __launch_bounds__(256) void intsoftmax_kernel(
    const float* __restrict__ x,
    const float* __restrict__ s_ptr,
    const float* __restrict__ lo_bounds,
    const float* __restrict__ coeffs,   // [16][3], highest power first
    float* __restrict__ out,
    int rows)
{
    __shared__ float4 sc[16];
    __shared__ float slo[16];
    __shared__ float etab[TSIZE];

    const int tid = threadIdx.x;
    if (tid < 16) {
        sc[tid] = make_float4(coeffs[tid * 3 + 0],
                              coeffs[tid * 3 + 1],
                              coeffs[tid * 3 + 2], 0.0f);
        slo[tid] = lo_bounds[tid];
    }
    __syncthreads();

    // Build e-table: etab[i] = e(i - (TSIZE-1)), exact reference ops.
    for (int i = tid; i < TSIZE; i += 256) {
        const float xv = (float)(i - (TSIZE - 1));
        int seg = 0;
#pragma unroll
        for (int j = 1; j < 16; ++j) seg += (xv >= slo[j]) ? 1 : 0;
        const float4 c = sc[seg];
        float r = __fadd_rn(__fmul_rn(c.x, xv), c.y);
        r = __fadd_rn(__fmul_rn(r, xv), c.z);
        etab[i] = floorf(fmaxf(r, 0.0f) * (1.0f / 32768.0f));
    }
    __syncthreads();

    if (blockIdx.x == 0 && tid == 0) {
        out[(size_t)rows * ROW] = 0.0078125f;  // second tuple output: s_out
    }

    const float s = s_ptr[0];
    const float rcp = __fdiv_rn(1.0f, s);  // RN(1/s), once

    const int wave = tid >> 6;
    const int lane = tid & 63;
    const long long row = (long long)blockIdx.x * WPB + wave;
    if (row >= rows) return;

    const float4* __restrict__ xr = (const float4*)(x + row * (long long)ROW);

    // x_int = floor(RN(x/s)) via Markstein correctly-rounded division
    float xi[16];
#pragma unroll
    for (int c4 = 0; c4 < 4; ++c4) {
        const float4 v = xr[c4 * 64 + lane];
        {
            const float q0 = __fmul_rn(v.x, rcp);
            xi[c4*4+0] = floorf(__builtin_fmaf(__builtin_fmaf(-s, q0, v.x), rcp, q0));
        }
        {
            const float q0 = __fmul_rn(v.y, rcp);
            xi[c4*4+1] = floorf(__builtin_fmaf(__builtin_fmaf(-s, q0, v.y), rcp, q0));
        }
        {
            const float q0 = __fmul_rn(v.z, rcp);
            xi[c4*4+2] = floorf(__builtin_fmaf(__builtin_fmaf(-s, q0, v.z), rcp, q0));
        }
        {
            const float q0 = __fmul_rn(v.w, rcp);
            xi[c4*4+3] = floorf(__builtin_fmaf(__builtin_fmaf(-s, q0, v.w), rcp, q0));
        }
    }

    // rowwise max (exact: integer-valued floats)
    float m = xi[0];
#pragma unroll
    for (int k = 1; k < 16; ++k) m = fmaxf(m, xi[k]);
#pragma unroll
    for (int off = 32; off >= 1; off >>= 1)
        m = fmaxf(m, __shfl_xor(m, off, 64));

    // table indices; imin tracks whether any element is below table range
    int idx[16];
    int imin = 0;
#pragma unroll
    for (int k = 0; k < 16; ++k) {
        idx[k] = (int)(xi[k] - m) + (TSIZE - 1);  // exact int-valued subtract
        imin = min(imin, idx[k]);
    }

    float e[16];
    float psum = 0.0f;
    if (__builtin_expect(!__any(imin < 0), 1)) {
        // fast path: pure table lookups
#pragma unroll
        for (int k = 0; k < 16; ++k) {
            e[k] = etab[idx[k]];
            psum += e[k];
        }
    } else {
        // exact fallback (wave-uniform branch; ~never taken for sane data)
#pragma unroll
        for (int k = 0; k < 16; ++k) {
            const float xv = xi[k] - m;
            int seg = 0;
#pragma unroll
            for (int j = 1; j < 16; ++j) seg += (xv >= slo[j]) ? 1 : 0;
            const float4 c = sc[seg];
            float r = __fadd_rn(__fmul_rn(c.x, xv), c.y);
            r = __fadd_rn(__fmul_rn(r, xv), c.z);
            e[k] = floorf(fmaxf(r, 0.0f) * (1.0f / 32768.0f));
            psum += e[k];
        }
    }

    // rowwise sum (exact small-int f32, order-free)
    float sum = psum;
#pragma unroll
    for (int off = 32; off >= 1; off >>= 1)
        sum += __shfl_xor(sum, off, 64);

    const float factor = floorf(__fdiv_rn(4294967296.0f, fmaxf(sum, 1.0f)));

    // softmax_int = floor(RN(e*factor) / 2^25); out = softmax_int * 2^-7
    f32x4* const orow_v = (f32x4*)(out + row * (long long)ROW);
#pragma unroll
    for (int c4 = 0; c4 < 4; ++c4) {
        f32x4 o;
        o.x = floorf(__fmul_rn(e[c4*4+0], factor) * (1.0f/33554432.0f)) * 0.0078125f;
        o.y = floorf(__fmul_rn(e[c4*4+1], factor) * (1.0f/33554432.0f)) * 0.0078125f;
        o.z = floorf(__fmul_rn(e[c4*4+2], factor) * (1.0f/33554432.0f)) * 0.0078125f;
        o.w = floorf(__fmul_rn(e[c4*4+3], factor) * (1.0f/33554432.0f)) * 0.0078125f;
        __builtin_nontemporal_store(o, orow_v + c4 * 64 + lane);
    }
}

extern "C" void kernel_launch(void* const* d_in, const int* in_sizes, int n_in,
                              void* d_out, int out_size, void* d_ws, size_t ws_size,
                              hipStream_t stream) {
    const float* x      = (const float*)d_in[0];
    const float* s      = (const float*)d_in[1];
    const float* lo     = (const float*)d_in[2];
    // d_in[3] = hi_bounds (unused: segments contiguous, lo alone decides)
    const float* coeffs = (const float*)d_in[4];
    float* out = (float*)d_out;

    const int n = in_sizes[0];
    const int rows = n / ROW;
    const int blocks = (rows + WPB - 1) / WPB;

    hipLaunchKernelGGL(intsoftmax_kernel, dim3(blocks), dim3(256), 0, stream,
                       x, s, lo, coeffs, out, rows);
}